// Round 5
// baseline (324.478 us; speedup 1.0000x reference)
//
#include <hip/hip_runtime.h>
#include <hip/hip_bf16.h>

__device__ __forceinline__ float bf2f(unsigned short u) {
    union { unsigned int i; float f; } v; v.i = ((unsigned int)u) << 16; return v.f;
}
__device__ __forceinline__ unsigned short f2bf(float f) {
    __hip_bfloat16 h = __float2bfloat16(f);
    return *reinterpret_cast<unsigned short*>(&h);
}

// ws: Q fp32 [b][g][pix][ci] (4 MB) | K bf16 (2 MB) | V bf16 (2 MB) | flag

// ---------------------------------------------------------------------------
// flag: detect input dtype from wq bit patterns. bf16 weights -> |x| small;
// fp32 weights -> even shorts are mantissa halves, decode huge w.h.p.
// ---------------------------------------------------------------------------
__global__ void flag_kernel(const unsigned short* __restrict__ wq,
                            int* __restrict__ flagp)
{
    if (threadIdx.x == 0) {
        float mx = 0.f;
        for (int i = 0; i < 64; ++i) mx = fmaxf(mx, fabsf(bf2f(wq[2 * i])));
        *flagp = (mx > 1000.f) ? 1 : 0;
    }
}

// ---------------------------------------------------------------------------
// conv: three 1x1 convs, dtype-adaptive loads, fp32 accumulate.
// Q -> fp32, K/V -> bf16, layout [b][g][pix][ci].
// grid (256 pixel-tiles, 3 mats), block 256.
// ---------------------------------------------------------------------------
__global__ __launch_bounds__(256) void conv1x1_kernel(
    const void* __restrict__ fmv,
    const void* __restrict__ wqv, const void* __restrict__ wkv,
    const void* __restrict__ wvv,
    const int* __restrict__ flagp,
    float* __restrict__ Qout,
    unsigned short* __restrict__ K0,
    unsigned short* __restrict__ V0)
{
    const int sel = blockIdx.y;
    const void* W = (sel == 0) ? wqv : ((sel == 1) ? wkv : wvv);
    const int c0 = (sel == 0) ? 128 : 0;   // Q reads fm_t1, K/V read fm_t0
    const int f = *flagp;

    __shared__ float w_s[128 * 68];
    __shared__ float x_s[32 * 68];

    const int tid = threadIdx.x;
    const int P0  = blockIdx.x * 32;
    const int b   = P0 >> 12;
    const int hw0 = P0 & 4095;
    const int p   = tid & 31;
    const int og  = tid >> 5;

    float acc[16];
    #pragma unroll
    for (int j = 0; j < 16; ++j) acc[j] = 0.f;

    for (int ch0 = 0; ch0 < 128; ch0 += 64) {
        // stage weights: 128 out x 64 in -> fp32 LDS
        if (f) {
            const float* Wf = (const float*)W;
            #pragma unroll
            for (int k = 0; k < 4; ++k) {
                const int oct = tid + k * 256;   // 0..1023, 8 floats each
                const int o = oct >> 3, c8 = oct & 7;
                float4 a = *(const float4*)(Wf + o * 128 + ch0 + c8 * 8);
                float4 bq = *(const float4*)(Wf + o * 128 + ch0 + c8 * 8 + 4);
                float* d = &w_s[o * 68 + c8 * 8];
                *(float4*)d = a; *(float4*)(d + 4) = bq;
            }
        } else {
            const unsigned short* Wh = (const unsigned short*)W;
            #pragma unroll
            for (int k = 0; k < 4; ++k) {
                const int oct = tid + k * 256;
                const int o = oct >> 3, c8 = oct & 7;
                uint4 v = *(const uint4*)(Wh + o * 128 + ch0 + c8 * 8);
                const unsigned short* u = (const unsigned short*)&v;
                float* d = &w_s[o * 68 + c8 * 8];
                #pragma unroll
                for (int j = 0; j < 8; ++j) d[j] = bf2f(u[j]);
            }
        }
        // stage + transpose x: 32 px x 64 ch
        {
            const int c = tid >> 2, chunk = tid & 3;
            const size_t base = (((size_t)(b * 256 + c0 + ch0 + c)) << 12)
                              + hw0 + chunk * 8;
            float xv[8];
            if (f) {
                const float* s = (const float*)fmv;
                float4 a = *(const float4*)(s + base);
                float4 bq = *(const float4*)(s + base + 4);
                xv[0]=a.x; xv[1]=a.y; xv[2]=a.z; xv[3]=a.w;
                xv[4]=bq.x; xv[5]=bq.y; xv[6]=bq.z; xv[7]=bq.w;
            } else {
                const unsigned short* s = (const unsigned short*)fmv;
                uint4 a = *(const uint4*)(s + base);
                const unsigned short* u = (const unsigned short*)&a;
                #pragma unroll
                for (int k = 0; k < 8; ++k) xv[k] = bf2f(u[k]);
            }
            #pragma unroll
            for (int k = 0; k < 8; ++k) x_s[(chunk * 8 + k) * 68 + c] = xv[k];
        }
        __syncthreads();
        #pragma unroll
        for (int c8 = 0; c8 < 8; ++c8) {
            float4 xa = *(const float4*)(&x_s[p * 68 + c8 * 8]);
            float4 xb = *(const float4*)(&x_s[p * 68 + c8 * 8 + 4]);
            #pragma unroll
            for (int j = 0; j < 16; ++j) {
                const float* wr = &w_s[(og * 16 + j) * 68 + c8 * 8];
                float4 wa = *(const float4*)wr;
                float4 wb = *(const float4*)(wr + 4);
                acc[j] += xa.x*wa.x + xa.y*wa.y + xa.z*wa.z + xa.w*wa.w
                        + xb.x*wb.x + xb.y*wb.y + xb.z*wb.z + xb.w*wb.w;
            }
        }
        __syncthreads();
    }

    const size_t obase = ((size_t)(((b * 8 + og) << 12) + hw0 + p)) << 4;
    if (sel == 0) {
        float* dst = Qout + obase;
        #pragma unroll
        for (int j = 0; j < 16; j += 4)
            *(float4*)(dst + j) = make_float4(acc[j], acc[j+1], acc[j+2], acc[j+3]);
    } else {
        unsigned short tmp[16];
        #pragma unroll
        for (int j = 0; j < 16; ++j) tmp[j] = f2bf(acc[j]);
        unsigned short* dst = ((sel == 1) ? K0 : V0) + obase;
        *(uint4*)dst       = *(const uint4*)tmp;
        *(uint4*)(dst + 8) = *(const uint4*)(tmp + 8);
    }
}

// ---------------------------------------------------------------------------
// attn: one thread per (b,g,h,w); bf16 K/V; row-batched loads for ILP;
// OOB fragments zero-filled so dot/axpy run unconditionally.
// block 256 = 4 rows x 64 cols; grid (16, 8, 2).
// ---------------------------------------------------------------------------
struct KV16 { uint4 a, b; };
__device__ __forceinline__ KV16 ld16(const unsigned short* p) {
    KV16 r; r.a = *(const uint4*)p; r.b = *(const uint4*)(p + 8); return r;
}
__device__ __forceinline__ KV16 zero16() {
    KV16 r; r.a = make_uint4(0,0,0,0); r.b = make_uint4(0,0,0,0); return r;
}
__device__ __forceinline__ float dotq(const float* q, const KV16& k) {
    const unsigned short* u = (const unsigned short*)&k;
    float s = 0.f;
    #pragma unroll
    for (int c = 0; c < 16; ++c) s += q[c] * bf2f(u[c]);
    return s;
}
__device__ __forceinline__ void axpyq(float* acc, float wgt, const KV16& v) {
    const unsigned short* u = (const unsigned short*)&v;
    #pragma unroll
    for (int c = 0; c < 16; ++c) acc[c] += wgt * bf2f(u[c]);
}

__global__ __launch_bounds__(256) void attn_kernel(
    const float* __restrict__ Q,
    const unsigned short* __restrict__ K0,
    const unsigned short* __restrict__ V0,
    const void* __restrict__ rhv,
    const void* __restrict__ rwv,
    const int* __restrict__ flagp,
    void* __restrict__ outv)
{
    const int tid = threadIdx.x;
    const int w = tid & 63;
    const int h = blockIdx.x * 4 + (tid >> 6);
    const int g = blockIdx.y;
    const int b = blockIdx.z;
    const int f = *flagp;

    const size_t slab = ((size_t)(b * 8 + g)) << 16;
    const float* qptr = Q + slab + (size_t)(h * 64 + w) * 16;

    float qr[16];
    #pragma unroll
    for (int ci = 0; ci < 16; ++ci) qr[ci] = qptr[ci];

    // qrel[t] = q . rel[:,t]  (rel_h for g<4 depends on i; rel_w on j)
    float qrel[7];
    {
        const int roff = (g < 4) ? g * 112 : (g - 4) * 112;
        if (f) {
            const float* rel = ((g < 4) ? (const float*)rhv : (const float*)rwv) + roff;
            #pragma unroll
            for (int t = 0; t < 7; ++t) {
                float s = 0.f;
                #pragma unroll
                for (int ci = 0; ci < 16; ++ci) s += qr[ci] * rel[ci * 7 + t];
                qrel[t] = s;
            }
        } else {
            const unsigned short* rel =
                ((g < 4) ? (const unsigned short*)rhv : (const unsigned short*)rwv) + roff;
            #pragma unroll
            for (int t = 0; t < 7; ++t) {
                float s = 0.f;
                #pragma unroll
                for (int ci = 0; ci < 16; ++ci) s += qr[ci] * bf2f(rel[ci * 7 + t]);
                qrel[t] = s;
            }
        }
    }

    const unsigned short* Kp = K0 + slab;
    const unsigned short* Vp = V0 + slab;

    float acc[16];
    #pragma unroll
    for (int ci = 0; ci < 16; ++ci) acc[ci] = 0.f;

    // ---- main 7x7 window ----
    {
        float sc[49];
        float mx = -3.4e38f;
        #pragma unroll
        for (int i = 0; i < 7; ++i) {
            const int y = h + i - 3;
            KV16 kr[7];
            #pragma unroll
            for (int j = 0; j < 7; ++j) {
                const int x = w + j - 3;
                kr[j] = (y >= 0 && y < 64 && x >= 0 && x < 64)
                      ? ld16(Kp + (size_t)(y * 64 + x) * 16) : zero16();
            }
            #pragma unroll
            for (int j = 0; j < 7; ++j) {
                float d = dotq(qr, kr[j]) + qrel[(g < 4) ? i : j];
                sc[i * 7 + j] = d;
                mx = fmaxf(mx, d);
            }
        }
        float den = 0.f;
        #pragma unroll
        for (int k = 0; k < 49; ++k) { sc[k] = __expf(sc[k] - mx); den += sc[k]; }
        const float inv = 1.f / den;
        #pragma unroll
        for (int i = 0; i < 7; ++i) {
            const int y = h + i - 3;
            KV16 vr[7];
            #pragma unroll
            for (int j = 0; j < 7; ++j) {
                const int x = w + j - 3;
                vr[j] = (y >= 0 && y < 64 && x >= 0 && x < 64)
                      ? ld16(Vp + (size_t)(y * 64 + x) * 16) : zero16();
            }
            #pragma unroll
            for (int j = 0; j < 7; ++j)
                axpyq(acc, sc[i * 7 + j] * inv, vr[j]);
        }
    }
    // ---- refine row (w offsets) ----
    {
        float sc[15];
        float mx = -3.4e38f;
        KV16 kr[15];
        #pragma unroll
        for (int j = 0; j < 15; ++j) {
            const int x = w + j - 7;
            kr[j] = (x >= 0 && x < 64) ? ld16(Kp + (size_t)(h * 64 + x) * 16) : zero16();
        }
        #pragma unroll
        for (int j = 0; j < 15; ++j) {
            const int x = w + j - 7;
            float d = (x >= 0 && x < 64) ? dotq(qr, kr[j]) : 0.f;
            sc[j] = d; mx = fmaxf(mx, d);
        }
        float den = 0.f;
        #pragma unroll
        for (int j = 0; j < 15; ++j) { sc[j] = __expf(sc[j] - mx); den += sc[j]; }
        const float inv = 1.f / den;
        #pragma unroll
        for (int j = 0; j < 15; ++j) {
            const int x = w + j - 7;
            KV16 vv = (x >= 0 && x < 64) ? ld16(Vp + (size_t)(h * 64 + x) * 16) : zero16();
            axpyq(acc, sc[j] * inv, vv);
        }
    }
    // ---- refine col (h offsets) ----
    {
        float sc[15];
        float mx = -3.4e38f;
        KV16 kr[15];
        #pragma unroll
        for (int i = 0; i < 15; ++i) {
            const int y = h + i - 7;
            kr[i] = (y >= 0 && y < 64) ? ld16(Kp + (size_t)(y * 64 + w) * 16) : zero16();
        }
        #pragma unroll
        for (int i = 0; i < 15; ++i) {
            const int y = h + i - 7;
            float d = (y >= 0 && y < 64) ? dotq(qr, kr[i]) : 0.f;
            sc[i] = d; mx = fmaxf(mx, d);
        }
        float den = 0.f;
        #pragma unroll
        for (int i = 0; i < 15; ++i) { sc[i] = __expf(sc[i] - mx); den += sc[i]; }
        const float inv = 1.f / den;
        #pragma unroll
        for (int i = 0; i < 15; ++i) {
            const int y = h + i - 7;
            KV16 vv = (y >= 0 && y < 64) ? ld16(Vp + (size_t)(y * 64 + w) * 16) : zero16();
            axpyq(acc, sc[i] * inv, vv);
        }
    }

    // store: out[b][g*16+ci][h][w], dtype per flag
    const size_t obase = (((size_t)(b * 128 + g * 16)) << 12) + h * 64 + w;
    if (f) {
        float* op = (float*)outv + obase;
        #pragma unroll
        for (int ci = 0; ci < 16; ++ci) op[(size_t)ci << 12] = acc[ci];
    } else {
        unsigned short* op = (unsigned short*)outv + obase;
        #pragma unroll
        for (int ci = 0; ci < 16; ++ci) op[(size_t)ci << 12] = f2bf(acc[ci]);
    }
}

// ---------------------------------------------------------------------------
extern "C" void kernel_launch(void* const* d_in, const int* in_sizes, int n_in,
                              void* d_out, int out_size, void* d_ws, size_t ws_size,
                              hipStream_t stream) {
    (void)in_sizes; (void)n_in; (void)out_size; (void)ws_size;
    float* Q = (float*)d_ws;                               // 1048576 floats
    unsigned short* K0 = (unsigned short*)(Q + 1048576);   // 1048576 shorts
    unsigned short* V0 = K0 + 1048576;                     // 1048576 shorts
    int* flagp = (int*)(V0 + 1048576);

    flag_kernel<<<dim3(1), dim3(64), 0, stream>>>(
        (const unsigned short*)d_in[1], flagp);
    conv1x1_kernel<<<dim3(256, 3, 1), dim3(256), 0, stream>>>(
        d_in[0], d_in[1], d_in[2], d_in[3], flagp, Q, K0, V0);
    attn_kernel<<<dim3(16, 8, 2), dim3(256), 0, stream>>>(
        Q, K0, V0, d_in[4], d_in[5], flagp, d_out);
}

// Round 6
// 115.298 us; speedup vs baseline: 2.8142x; 2.8142x over previous
//
#include <hip/hip_runtime.h>
#include <hip/hip_bf16.h>

__device__ __forceinline__ float bf2f(unsigned short u) {
    union { unsigned int i; float f; } v; v.i = ((unsigned int)u) << 16; return v.f;
}
__device__ __forceinline__ unsigned short f2bf(float f) {
    __hip_bfloat16 h = __float2bfloat16(f);
    return *reinterpret_cast<unsigned short*>(&h);
}

// ws: Q fp32 [b][g][pix][ci] (4 MB) | K bf16 (2 MB) | V bf16 (2 MB)

// ---------------------------------------------------------------------------
// conv: three 1x1 convs, fp32 in/weights, fp32 accum.
// Register-tiled GEMM: block = 128 out-ch x 64 px, thread = 8 ch x 4 px.
// LDS k-major tiles: w_s[k][o] (64x132), x_s[k][px] (64x68). Two K-halves.
// Q -> fp32, K/V -> bf16, layout [b][g][pix][ci]. grid (128 px-tiles, 3).
// ---------------------------------------------------------------------------
__global__ __launch_bounds__(256) void conv_kernel(
    const float* __restrict__ fm,
    const float* __restrict__ wq, const float* __restrict__ wk,
    const float* __restrict__ wv,
    float* __restrict__ Qout,
    unsigned short* __restrict__ K0,
    unsigned short* __restrict__ V0)
{
    const int sel = blockIdx.y;
    const float* W = (sel == 0) ? wq : ((sel == 1) ? wk : wv);
    const int c0 = (sel == 0) ? 128 : 0;   // Q reads fm_t1, K/V read fm_t0

    __shared__ float w_s[64 * 132];   // [k][o], o stride 132
    __shared__ float x_s[64 * 68];    // [k][px], px stride 68

    const int tid = threadIdx.x;
    const int P0  = blockIdx.x * 64;  // one full row of one image
    const int b   = P0 >> 12;
    const int hw0 = P0 & 4095;

    float acc[8][4];
    #pragma unroll
    for (int i = 0; i < 8; ++i)
        #pragma unroll
        for (int j = 0; j < 4; ++j) acc[i][j] = 0.f;

    const int ocb = (tid >> 4) * 8;   // out-ch base (0,8,...,120)
    const int pxb = (tid & 15) * 4;   // px base (0,4,...,60)

    for (int kh = 0; kh < 128; kh += 64) {
        // stage weights transposed: w_s[k][o]
        {
            const int o    = tid >> 1;
            const int koff = (tid & 1) * 32;
            #pragma unroll
            for (int i = 0; i < 8; ++i) {
                float4 v = *(const float4*)(W + o * 128 + kh + koff + i * 4);
                w_s[(koff + i * 4 + 0) * 132 + o] = v.x;
                w_s[(koff + i * 4 + 1) * 132 + o] = v.y;
                w_s[(koff + i * 4 + 2) * 132 + o] = v.z;
                w_s[(koff + i * 4 + 3) * 132 + o] = v.w;
            }
        }
        // stage x: x_s[k][px] — matches global [ch][px] layout, fully vector
        {
            const int c  = tid >> 2;
            const int pc = (tid & 3) * 16;
            const float* src = fm + (((size_t)(b * 256 + c0 + kh + c)) << 12) + hw0 + pc;
            #pragma unroll
            for (int i = 0; i < 4; ++i)
                *(float4*)(&x_s[c * 68 + pc + i * 4]) = *(const float4*)(src + i * 4);
        }
        __syncthreads();
        #pragma unroll 8
        for (int k = 0; k < 64; ++k) {
            const float* kw = &w_s[k * 132 + ocb];
            float4 wa = *(const float4*)kw;
            float4 wb = *(const float4*)(kw + 4);
            float4 xv = *(const float4*)(&x_s[k * 68 + pxb]);
            const float wf[8] = {wa.x, wa.y, wa.z, wa.w, wb.x, wb.y, wb.z, wb.w};
            const float xf[4] = {xv.x, xv.y, xv.z, xv.w};
            #pragma unroll
            for (int i = 0; i < 8; ++i)
                #pragma unroll
                for (int j = 0; j < 4; ++j) acc[i][j] += wf[i] * xf[j];
        }
        __syncthreads();
    }

    // epilogue: out[b][g][pix][ci], g = ocb>>4, ci base = ocb&8
    const int g   = ocb >> 4;
    const int lci = ocb & 8;
    #pragma unroll
    for (int pj = 0; pj < 4; ++pj) {
        const int hw = hw0 + pxb + pj;
        const size_t base = ((((size_t)(b * 8 + g)) << 12) + hw) * 16 + lci;
        if (sel == 0) {
            *(float4*)(Qout + base)     = make_float4(acc[0][pj], acc[1][pj], acc[2][pj], acc[3][pj]);
            *(float4*)(Qout + base + 4) = make_float4(acc[4][pj], acc[5][pj], acc[6][pj], acc[7][pj]);
        } else {
            unsigned short tmp[8];
            #pragma unroll
            for (int i = 0; i < 8; ++i) tmp[i] = f2bf(acc[i][pj]);
            unsigned short* dst = ((sel == 1) ? K0 : V0) + base;
            *(uint4*)dst = *(const uint4*)tmp;
        }
    }
}

// ---------------------------------------------------------------------------
// attn: one thread per (b,g,h,w) per PART. part 0 = main 7x7 (rel bias),
// part 1 = refine row, part 2 = refine col. Each part atomically adds its
// softmax-weighted sum into the zero-initialized fp32 output.
// block 256 = 4 rows x 64 cols; grid (16, 8, 6) with z = b*3 + part.
// ---------------------------------------------------------------------------
struct KV16 { uint4 a, b; };
__device__ __forceinline__ KV16 ld16(const unsigned short* p) {
    KV16 r; r.a = *(const uint4*)p; r.b = *(const uint4*)(p + 8); return r;
}
__device__ __forceinline__ float dotq(const float* q, const KV16& k) {
    const unsigned short* u = (const unsigned short*)&k;
    float s = 0.f;
    #pragma unroll
    for (int c = 0; c < 16; ++c) s += q[c] * bf2f(u[c]);
    return s;
}
__device__ __forceinline__ void axpyq(float* acc, float wgt, const KV16& v) {
    const unsigned short* u = (const unsigned short*)&v;
    #pragma unroll
    for (int c = 0; c < 16; ++c) acc[c] += wgt * bf2f(u[c]);
}

__global__ __launch_bounds__(256) void attn_kernel(
    const float* __restrict__ Q,
    const unsigned short* __restrict__ K0,
    const unsigned short* __restrict__ V0,
    const float* __restrict__ rel_h,
    const float* __restrict__ rel_w,
    float* __restrict__ out)
{
    const int tid  = threadIdx.x;
    const int w    = tid & 63;
    const int h    = blockIdx.x * 4 + (tid >> 6);
    const int g    = blockIdx.y;
    const int b    = blockIdx.z / 3;
    const int part = blockIdx.z % 3;

    const size_t slab = ((size_t)(b * 8 + g)) << 16;
    const float* qptr = Q + slab + (size_t)(h * 64 + w) * 16;

    float qr[16];
    #pragma unroll
    for (int ci = 0; ci < 16; ++ci) qr[ci] = qptr[ci];

    const unsigned short* Kp = K0 + slab;
    const unsigned short* Vp = V0 + slab;

    float acc[16];
    #pragma unroll
    for (int ci = 0; ci < 16; ++ci) acc[ci] = 0.f;

    if (part == 0) {
        // qrel[t] = q . rel[:,t]; rel_h for g<4 (depends on i), rel_w else (j)
        float qrel[7];
        const float* rel = (g < 4) ? (rel_h + g * 112) : (rel_w + (g - 4) * 112);
        #pragma unroll
        for (int t = 0; t < 7; ++t) {
            float s = 0.f;
            #pragma unroll
            for (int ci = 0; ci < 16; ++ci) s += qr[ci] * rel[ci * 7 + t];
            qrel[t] = s;
        }
        float sc[49];
        float mx = -3.4e38f;
        #pragma unroll
        for (int i = 0; i < 7; ++i) {
            const int y = h + i - 3;
            #pragma unroll
            for (int j = 0; j < 7; ++j) {
                const int x = w + j - 3;
                float d = 0.f;
                if (y >= 0 && y < 64 && x >= 0 && x < 64)
                    d = dotq(qr, ld16(Kp + (size_t)(y * 64 + x) * 16));
                d += qrel[(g < 4) ? i : j];
                sc[i * 7 + j] = d;
                mx = fmaxf(mx, d);
            }
        }
        float den = 0.f;
        #pragma unroll
        for (int k = 0; k < 49; ++k) { sc[k] = __expf(sc[k] - mx); den += sc[k]; }
        const float inv = 1.f / den;
        #pragma unroll
        for (int i = 0; i < 7; ++i) {
            const int y = h + i - 3;
            #pragma unroll
            for (int j = 0; j < 7; ++j) {
                const int x = w + j - 3;
                if (y >= 0 && y < 64 && x >= 0 && x < 64)
                    axpyq(acc, sc[i * 7 + j] * inv, ld16(Vp + (size_t)(y * 64 + x) * 16));
            }
        }
    } else if (part == 1) {
        // refine row (w offsets)
        float sc[15];
        float mx = -3.4e38f;
        #pragma unroll
        for (int j = 0; j < 15; ++j) {
            const int x = w + j - 7;
            float d = 0.f;
            if (x >= 0 && x < 64)
                d = dotq(qr, ld16(Kp + (size_t)(h * 64 + x) * 16));
            sc[j] = d; mx = fmaxf(mx, d);
        }
        float den = 0.f;
        #pragma unroll
        for (int j = 0; j < 15; ++j) { sc[j] = __expf(sc[j] - mx); den += sc[j]; }
        const float inv = 1.f / den;
        #pragma unroll
        for (int j = 0; j < 15; ++j) {
            const int x = w + j - 7;
            if (x >= 0 && x < 64)
                axpyq(acc, sc[j] * inv, ld16(Vp + (size_t)(h * 64 + x) * 16));
        }
    } else {
        // refine col (h offsets)
        float sc[15];
        float mx = -3.4e38f;
        #pragma unroll
        for (int i = 0; i < 15; ++i) {
            const int y = h + i - 7;
            float d = 0.f;
            if (y >= 0 && y < 64)
                d = dotq(qr, ld16(Kp + (size_t)(y * 64 + w) * 16));
            sc[i] = d; mx = fmaxf(mx, d);
        }
        float den = 0.f;
        #pragma unroll
        for (int i = 0; i < 15; ++i) { sc[i] = __expf(sc[i] - mx); den += sc[i]; }
        const float inv = 1.f / den;
        #pragma unroll
        for (int i = 0; i < 15; ++i) {
            const int y = h + i - 7;
            if (y >= 0 && y < 64)
                axpyq(acc, sc[i] * inv, ld16(Vp + (size_t)(y * 64 + w) * 16));
        }
    }

    // accumulate: out[b][g*16+ci][h][w] += acc[ci]
    float* op = out + (((size_t)(b * 128 + g * 16)) << 12) + h * 64 + w;
    #pragma unroll
    for (int ci = 0; ci < 16; ++ci)
        atomicAdd(op + ((size_t)ci << 12), acc[ci]);
}

// ---------------------------------------------------------------------------
extern "C" void kernel_launch(void* const* d_in, const int* in_sizes, int n_in,
                              void* d_out, int out_size, void* d_ws, size_t ws_size,
                              hipStream_t stream) {
    (void)in_sizes; (void)n_in; (void)ws_size;
    const float* fm    = (const float*)d_in[0];
    const float* wq    = (const float*)d_in[1];
    const float* wk    = (const float*)d_in[2];
    const float* wv    = (const float*)d_in[3];
    const float* rel_h = (const float*)d_in[4];
    const float* rel_w = (const float*)d_in[5];

    float* Q = (float*)d_ws;                               // 1048576 floats
    unsigned short* K0 = (unsigned short*)(Q + 1048576);   // 1048576 shorts
    unsigned short* V0 = K0 + 1048576;                     // 1048576 shorts

    hipMemsetAsync(d_out, 0, (size_t)out_size * sizeof(float), stream);
    conv_kernel<<<dim3(128, 3, 1), dim3(256), 0, stream>>>(
        fm, wq, wk, wv, Q, K0, V0);
    attn_kernel<<<dim3(16, 8, 6), dim3(256), 0, stream>>>(
        Q, K0, V0, rel_h, rel_w, (float*)d_out);
}